// Round 12
// baseline (5108.229 us; speedup 1.0000x reference)
//
#include <hip/hip_runtime.h>
#include <hip/hip_bf16.h>

#define TT 512
#define BB 64
#define II 256
#define HH 1024
#define NWG 256
#define MB 16          // batches per WG (4 batch groups)
#define NJ 16          // hidden units per WG (64 j-tiles)
#define NR 64          // packed gate rows per WG (16 j x 4 gates, p = j*4+g)
#define KTOT 1280      // packed weight row: 256 (x) + 1024 (h)
#define WU 120         // Wh k-units (16B) kept in LDS; units 120..127 in regs
#define WROWB 1920     // bytes per Wl row (120 units)
#define HROWB 2048     // bytes per Hs row (128 units, bf16)
#define NFLAG 1024     // 4 groups x 64 gt x 4 waves
#define MAXTRY (1 << 20)

typedef __bf16 bf16x8 __attribute__((ext_vector_type(8)));
typedef float f32x4 __attribute__((ext_vector_type(4)));
typedef unsigned uint32x4 __attribute__((ext_vector_type(4)));

__device__ inline uint32x4 ld16_sc1(const void* p) {
  uint32x4 r;
  asm volatile("global_load_dwordx4 %0, %1, off sc1" : "=&v"(r) : "v"(p));
  return r;
}

// ---------------- prep kernels ----------------

__global__ __launch_bounds__(256) void k_cast_inputs(const float* __restrict__ in,
                                                     __hip_bfloat16* __restrict__ outp) {
  int i = (blockIdx.x * 256 + threadIdx.x) * 4;
  float4 v = *reinterpret_cast<const float4*>(in + i);
  outp[i + 0] = __float2bfloat16(v.x);
  outp[i + 1] = __float2bfloat16(v.y);
  outp[i + 2] = __float2bfloat16(v.z);
  outp[i + 3] = __float2bfloat16(v.w);
}

// Packed row p = j*4 + gate (gate order i,f,g,o), cols [0:256)=Wx, [256:1280)=Wh
__global__ __launch_bounds__(256) void k_pack_w(
    const float* __restrict__ wxi, const float* __restrict__ whi,
    const float* __restrict__ wxf, const float* __restrict__ whf,
    const float* __restrict__ wxg, const float* __restrict__ whg,
    const float* __restrict__ wxo, const float* __restrict__ who,
    __hip_bfloat16* __restrict__ Wp) {
  int t = blockIdx.x * 256 + threadIdx.x;   // 0 .. 4096*320
  int p = t / 320;
  int k4 = (t - p * 320) * 4;
  int j = p >> 2, gate = p & 3;
  const float* wx = (gate == 0) ? wxi : (gate == 1) ? wxf : (gate == 2) ? wxg : wxo;
  const float* wh = (gate == 0) ? whi : (gate == 1) ? whf : (gate == 2) ? whg : who;
  float4 v;
  if (k4 < II) v = *reinterpret_cast<const float4*>(wx + (size_t)j * II + k4);
  else         v = *reinterpret_cast<const float4*>(wh + (size_t)j * HH + (k4 - II));
  __hip_bfloat16* o = Wp + (size_t)p * KTOT + k4;
  o[0] = __float2bfloat16(v.x);
  o[1] = __float2bfloat16(v.y);
  o[2] = __float2bfloat16(v.z);
  o[3] = __float2bfloat16(v.w);
}

__global__ __launch_bounds__(256) void k_pack_bias_h0(
    const float* __restrict__ bii, const float* __restrict__ bhi,
    const float* __restrict__ bif, const float* __restrict__ bhf,
    const float* __restrict__ bg,  const float* __restrict__ bhg,
    const float* __restrict__ bio, const float* __restrict__ bho,
    const float* __restrict__ h0, float* __restrict__ biasp,
    __hip_bfloat16* __restrict__ hb, unsigned* __restrict__ flags) {
  int i = blockIdx.x * 256 + threadIdx.x;   // 0..65535
  if (i < 4096) {
    int j = i >> 2, gate = i & 3;
    const float* bi = (gate == 0) ? bii : (gate == 1) ? bif : (gate == 2) ? bg : bio;
    const float* bh = (gate == 0) ? bhi : (gate == 1) ? bhf : (gate == 2) ? bhg : bho;
    biasp[i] = bi[j] + bh[j];
  }
  if (i < NFLAG) flags[i] = 0;
  hb[i] = __float2bfloat16(h0[i]);
}

// ---------------- persistent recurrent kernel ----------------
// R8 tiling/protocol (proven, 2181us). Three latency-chain deltas:
//  1) direct scattered publish (per-thread 2B sc1) — no Ho LDS bounce.
//  2) publish-ack hidden under out-store + x-MFMA window; vmcnt(0)+flag after.
//  3) K-split staging: issue 8 loads, vmcnt(4), repack half1, raw s_barrier
//     (no vmcnt drain — half2 is in private regs), MFMA k0..63 while half2
//     flies, vmcnt(0), repack half2, s_barrier, loop-top does MFMA k64..127.
// Loop rotated: top = half2 MFMA + gate math; tail = stage + half1 MFMA.

__global__ __launch_bounds__(256, 1) void k_lstm(
    const __hip_bfloat16* __restrict__ xb,
    const __hip_bfloat16* __restrict__ Wp,
    const float* __restrict__ biasp,
    const float* __restrict__ c0,
    __hip_bfloat16* __restrict__ hbuf,    // 2 x (B,H) bf16 ping-pong
    unsigned* __restrict__ flags,         // 4 groups x 64 gt x 4 waves
    float* __restrict__ out)
{
  extern __shared__ __align__(16) char smem[];
  char* Wl = smem;                        // 122880: Wh 64 rows x 120 units, XOR-swz
  char* Hs = smem + 122880;               // 32768: staged h, 16 rows x 128 units bf16
  char* Zx = smem + 155648;               // 5120: per-wave z exchange

  const int tid = threadIdx.x;
  const int lane = tid & 63;
  const int wq = tid >> 6;
  const int bt = blockIdx.x >> 6;        // batch group 0..3
  const int gt = blockIdx.x & 63;        // j tile 0..63
  const int b0 = bt * MB;
  const int r0 = gt * NR;

  const int l15 = lane & 15;
  const int kqu = lane >> 4;             // 0..3 (16B unit within 32-k chunk)

  // ---- prologue: stage Wh k-units 0..119 -> Wl ----
  {
    const int u = tid & 127;
    const bool act = u < WU;
    uint32x4 wtmp[16];
#pragma unroll
    for (int q = 0; q < 16; ++q) {
      int row = q * 2 + (tid >> 7);
      if (act) wtmp[q] = *reinterpret_cast<const uint32x4*>(
          Wp + (size_t)(r0 + row) * KTOT + II + u * 8);
    }
#pragma unroll
    for (int q = 0; q < 16; ++q) {
      int row = q * 2 + (tid >> 7);
      if (act) *reinterpret_cast<uint32x4*>(Wl + row * WROWB + ((u ^ (row & 7)) << 4)) = wtmp[q];
    }
#pragma unroll
    for (int q = 0; q < 16; ++q) {
      int row = 32 + q * 2 + (tid >> 7);
      if (act) wtmp[q] = *reinterpret_cast<const uint32x4*>(
          Wp + (size_t)(r0 + row) * KTOT + II + u * 8);
    }
#pragma unroll
    for (int q = 0; q < 16; ++q) {
      int row = 32 + q * 2 + (tid >> 7);
      if (act) *reinterpret_cast<uint32x4*>(Wl + row * WROWB + ((u ^ (row & 7)) << 4)) = wtmp[q];
    }
  }

  // ---- wave's weights in registers: Wx (8 frags) + Wh tail units 120..127 ----
  const int brow = r0 + wq * 16 + l15;
  bf16x8 wxr[8], wht0, wht1;
  {
    const __hip_bfloat16* ws = Wp + (size_t)brow * KTOT + kqu * 8;
#pragma unroll
    for (int kk = 0; kk < 8; ++kk)
      wxr[kk] = *reinterpret_cast<const bf16x8*>(ws + kk * 32);
    wht0 = *reinterpret_cast<const bf16x8*>(ws + II + 960);
    wht1 = *reinterpret_cast<const bf16x8*>(ws + II + 992);
  }

  // ---- epilogue cell identity ----
  const int m_e = 4 * kqu + (lane & 3);            // batch 0..15
  const int tq = (lane >> 2) & 3;                  // j offset within wave
  const int j_g = gt * NJ + wq * 4 + tq;
  const int b_g = b0 + m_e;
  const float4 bias = *reinterpret_cast<const float4*>(biasp + j_g * 4);
  float c_reg = c0[(size_t)b_g * HH + j_g];

  // ---- fragment geometry ----
  const int hs_swz = l15 & 7;
  const int bn_row = wq * 16 + l15;
  const int bn_swz = bn_row & 7;
  char* ZxW = Zx + wq * 1280;

  // ---- prologue: stage h(0) rows [wq*4,+4) fully, coalesced sc1 ----
  {
    uint32x4 tmp[8];
#pragma unroll
    for (int q = 0; q < 8; ++q) {
      int rl = wq * 4 + (q & 3);
      int u = (q >> 2) * 64 + lane;
      tmp[q] = ld16_sc1(hbuf + (size_t)(b0 + rl) * HH + u * 8);
    }
    asm volatile("s_waitcnt vmcnt(0)" ::: "memory");
    __builtin_amdgcn_sched_barrier(0);
#pragma unroll
    for (int q = 0; q < 8; ++q) {
      int rl = wq * 4 + (q & 3);
      int u = (q >> 2) * 64 + lane;
      *reinterpret_cast<uint32x4*>(Hs + rl * HROWB + ((u ^ (rl & 7)) << 4)) = tmp[q];
    }
  }

  // ---- prologue: x-part MFMA for t=0 ----
  const __hip_bfloat16* xrowA = xb + (size_t)(b0 + l15) * (TT * II) + kqu * 8;
  f32x4 accs[4];
#pragma unroll
  for (int q = 0; q < 4; ++q) accs[q] = (f32x4){0.f, 0.f, 0.f, 0.f};
#pragma unroll
  for (int kk = 0; kk < 8; ++kk) {
    bf16x8 xa = *reinterpret_cast<const bf16x8*>(xrowA + kk * 32);
    accs[kk & 3] = __builtin_amdgcn_mfma_f32_16x16x32_bf16(xa, wxr[kk], accs[kk & 3], 0, 0, 0);
  }

  __syncthreads();

  // ---- prologue: half1 h-MFMA for t=0 (k-units 0..63) ----
#pragma unroll
  for (int kk = 0; kk < 16; ++kk) {
    int u = kk * 4 + kqu;
    bf16x8 a = *reinterpret_cast<const bf16x8*>(Hs + l15 * HROWB + ((u ^ hs_swz) << 4));
    bf16x8 b = *reinterpret_cast<const bf16x8*>(Wl + bn_row * WROWB + ((u ^ bn_swz) << 4));
    accs[kk & 3] = __builtin_amdgcn_mfma_f32_16x16x32_bf16(a, b, accs[kk & 3], 0, 0, 0);
  }

  for (int t = 0; t < TT; ++t) {
    // ---- A: half2 h-MFMA (k-units 64..127; x + half1 already in accs) ----
#pragma unroll
    for (int kk = 16; kk < 30; ++kk) {
      int u = kk * 4 + kqu;
      bf16x8 a = *reinterpret_cast<const bf16x8*>(Hs + l15 * HROWB + ((u ^ hs_swz) << 4));
      bf16x8 b = *reinterpret_cast<const bf16x8*>(Wl + bn_row * WROWB + ((u ^ bn_swz) << 4));
      accs[kk & 3] = __builtin_amdgcn_mfma_f32_16x16x32_bf16(a, b, accs[kk & 3], 0, 0, 0);
    }
    {
      int u = 120 + kqu;
      bf16x8 a = *reinterpret_cast<const bf16x8*>(Hs + l15 * HROWB + ((u ^ hs_swz) << 4));
      accs[2] = __builtin_amdgcn_mfma_f32_16x16x32_bf16(a, wht0, accs[2], 0, 0, 0);
    }
    {
      int u = 124 + kqu;
      bf16x8 a = *reinterpret_cast<const bf16x8*>(Hs + l15 * HROWB + ((u ^ hs_swz) << 4));
      accs[3] = __builtin_amdgcn_mfma_f32_16x16x32_bf16(a, wht1, accs[3], 0, 0, 0);
    }
    f32x4 acc = (accs[0] + accs[1]) + (accs[2] + accs[3]);

    // ---- B: in-wave z exchange via LDS (drains this wave's Hs reads too) ----
    *reinterpret_cast<f32x4*>(ZxW + l15 * 80 + kqu * 16) = acc;
    asm volatile("s_waitcnt lgkmcnt(0)" ::: "memory");
    __builtin_amdgcn_sched_barrier(0);
    float zi = *reinterpret_cast<const float*>(ZxW + (4 * tq + 0) * 80 + m_e * 4) + bias.x;
    float zf = *reinterpret_cast<const float*>(ZxW + (4 * tq + 1) * 80 + m_e * 4) + bias.y;
    float zg = *reinterpret_cast<const float*>(ZxW + (4 * tq + 2) * 80 + m_e * 4) + bias.z;
    float zo = *reinterpret_cast<const float*>(ZxW + (4 * tq + 3) * 80 + m_e * 4) + bias.w;

    float ig = 1.f / (1.f + __expf(-zi));
    float fg = 1.f / (1.f + __expf(-zf));
    float gg = 2.f / (1.f + __expf(-2.f * zg)) - 1.f;
    float og = 1.f / (1.f + __expf(-zo));
    c_reg = fg * c_reg + ig * gg;
    float tc = 2.f / (1.f + __expf(-2.f * c_reg)) - 1.f;
    float h = og * tc;

    if (t == TT - 1) {
      out[(size_t)b_g * (TT * HH) + (size_t)t * HH + j_g] = h;
      out[(size_t)BB * TT * HH + (size_t)b_g * HH + j_g] = h;
      out[(size_t)BB * TT * HH + BB * HH + (size_t)b_g * HH + j_g] = c_reg;
      break;
    }

    // ---- C: direct scattered publish (per-thread 2B sc1), NO ack yet ----
    const int nxt = (t + 1) & 1;
    const unsigned gen = (unsigned)(t + 1);
    {
      __hip_bfloat16 hb16 = __float2bfloat16(h);
      unsigned hv = (unsigned)*reinterpret_cast<unsigned short*>(&hb16);
      __hip_bfloat16* dst = hbuf + (size_t)nxt * (BB * HH) + (size_t)b_g * HH + j_g;
      asm volatile("global_store_short %0, %1, off sc1" :: "v"(dst), "v"(hv) : "memory");
    }

    // ---- D: ack hides under out store + x(t+1)-part MFMA ----
    out[(size_t)b_g * (TT * HH) + (size_t)t * HH + j_g] = h;
#pragma unroll
    for (int q = 0; q < 4; ++q) accs[q] = (f32x4){0.f, 0.f, 0.f, 0.f};
    {
      const __hip_bfloat16* xp = xrowA + (size_t)(t + 1) * II;
#pragma unroll
      for (int kk = 0; kk < 8; ++kk) {
        bf16x8 xa = *reinterpret_cast<const bf16x8*>(xp + kk * 32);
        accs[kk & 3] = __builtin_amdgcn_mfma_f32_16x16x32_bf16(xa, wxr[kk], accs[kk & 3], 0, 0, 0);
      }
    }
    asm volatile("s_waitcnt vmcnt(0)" ::: "memory");   // publish acked
    if (lane == 0) {
      asm volatile("global_store_dword %0, %1, off sc1"
                   :: "v"(flags + bt * 256 + gt * 4 + wq), "v"(gen) : "memory");
    }

    // ---- E: every wave polls its group's 256 flags (4 per lane) ----
    {
      const unsigned* fp = flags + bt * 256 + lane * 4;
      int tries = 0;
      uint32x4 f;
      for (;;) {
        asm volatile("global_load_dwordx4 %0, %1, off sc1\n\ts_waitcnt vmcnt(0)"
                     : "=&v"(f) : "v"(fp) : "memory");
        int ok = (f.x >= gen) && (f.y >= gen) && (f.z >= gen) && (f.w >= gen);
        if (__all(ok) || ++tries > MAXTRY) break;
      }
    }

    // ---- F: K-split staging. Issue all 8 loads (q0..3 = half1 k0..63) ----
    {
      uint32x4 tmp[8];
      const __hip_bfloat16* hsrc = hbuf + (size_t)nxt * (BB * HH);
#pragma unroll
      for (int q = 0; q < 8; ++q) {
        int rl = wq * 4 + (q & 3);
        int u = (q >> 2) * 64 + lane;
        tmp[q] = ld16_sc1(hsrc + (size_t)(b0 + rl) * HH + u * 8);
      }
      asm volatile("s_waitcnt vmcnt(4)" ::: "memory");   // half1 landed
      __builtin_amdgcn_sched_barrier(0);
#pragma unroll
      for (int q = 0; q < 4; ++q) {
        int rl = wq * 4 + q;
        *reinterpret_cast<uint32x4*>(Hs + rl * HROWB + ((lane ^ (rl & 7)) << 4)) = tmp[q];
      }
      asm volatile("s_waitcnt lgkmcnt(0)" ::: "memory");
      __builtin_amdgcn_s_barrier();                      // S2a: half1 visible

      // half1 h-MFMA (k 0..63) while half2 is still in flight
#pragma unroll
      for (int kk = 0; kk < 16; ++kk) {
        int u = kk * 4 + kqu;
        bf16x8 a = *reinterpret_cast<const bf16x8*>(Hs + l15 * HROWB + ((u ^ hs_swz) << 4));
        bf16x8 b = *reinterpret_cast<const bf16x8*>(Wl + bn_row * WROWB + ((u ^ bn_swz) << 4));
        accs[kk & 3] = __builtin_amdgcn_mfma_f32_16x16x32_bf16(a, b, accs[kk & 3], 0, 0, 0);
      }

      asm volatile("s_waitcnt vmcnt(0)" ::: "memory");   // half2 landed
      __builtin_amdgcn_sched_barrier(0);
#pragma unroll
      for (int q = 4; q < 8; ++q) {
        int rl = wq * 4 + (q & 3);
        *reinterpret_cast<uint32x4*>(Hs + rl * HROWB + (((64 + lane) ^ (rl & 7)) << 4)) = tmp[q];
      }
      asm volatile("s_waitcnt lgkmcnt(0)" ::: "memory");
      __builtin_amdgcn_s_barrier();                      // S2b: half2 visible
    }
  }
}

// ---------------- launcher ----------------

extern "C" void kernel_launch(void* const* d_in, const int* in_sizes, int n_in,
                              void* d_out, int out_size, void* d_ws, size_t ws_size,
                              hipStream_t stream) {
  (void)in_sizes; (void)n_in; (void)out_size; (void)ws_size;
  const float* inputs = (const float*)d_in[0];
  const float* h0 = (const float*)d_in[1];
  const float* c0 = (const float*)d_in[2];
  const float* w_ii = (const float*)d_in[3];
  const float* w_hi = (const float*)d_in[4];
  const float* b_ii = (const float*)d_in[5];
  const float* b_hi = (const float*)d_in[6];
  const float* w_if = (const float*)d_in[7];
  const float* w_hf = (const float*)d_in[8];
  const float* b_if = (const float*)d_in[9];
  const float* b_hf = (const float*)d_in[10];
  const float* w_io = (const float*)d_in[11];
  const float* w_ho = (const float*)d_in[12];
  const float* b_io = (const float*)d_in[13];
  const float* b_ho = (const float*)d_in[14];
  const float* w_ig = (const float*)d_in[15];
  const float* w_hg = (const float*)d_in[16];
  const float* b_ig = (const float*)d_in[17];
  const float* b_hg = (const float*)d_in[18];

  char* ws = (char*)d_ws;
  __hip_bfloat16* xb    = (__hip_bfloat16*)ws;                    // 16,777,216 B
  __hip_bfloat16* Wp    = (__hip_bfloat16*)(ws + 16777216);       // 10,485,760 B
  float*          biasp = (float*)(ws + 27262976);                // 16,384 B
  __hip_bfloat16* hbuf  = (__hip_bfloat16*)(ws + 27279360);       // 262,144 B
  unsigned*       flags = (unsigned*)(ws + 27541504);             // 4,096 B
  float* out = (float*)d_out;

  k_cast_inputs<<<8192, 256, 0, stream>>>(inputs, xb);
  k_pack_w<<<5120, 256, 0, stream>>>(w_ii, w_hi, w_if, w_hf, w_ig, w_hg, w_io, w_ho, Wp);
  k_pack_bias_h0<<<256, 256, 0, stream>>>(b_ii, b_hi, b_if, b_hf, b_ig, b_hg,
                                          b_io, b_ho, h0, biasp, hbuf, flags);

  const int lds_bytes = 160768;
  hipFuncSetAttribute((const void*)k_lstm,
                      hipFuncAttributeMaxDynamicSharedMemorySize, lds_bytes);
  void* args[] = {(void*)&xb, (void*)&Wp, (void*)&biasp, (void*)&c0,
                  (void*)&hbuf, (void*)&flags, (void*)&out};
  hipError_t e = hipLaunchCooperativeKernel((void*)k_lstm, dim3(NWG), dim3(256),
                                            args, lds_bytes, stream);
  if (e != hipSuccess) {
    // Fallback: plain launch. 256 WGs at 1 WG/CU (LDS-bound) on 256 CUs are
    // de-facto co-resident; the barrier protocol is flag-based only.
    k_lstm<<<dim3(NWG), dim3(256), lds_bytes, stream>>>(xb, Wp, biasp, c0, hbuf, flags, out);
  }
}

// Round 13
// 1904.404 us; speedup vs baseline: 2.6823x; 2.6823x over previous
//
#include <hip/hip_runtime.h>
#include <hip/hip_bf16.h>

#define TT 512
#define BB 64
#define II 256
#define HH 1024
#define NWG 256
#define MB 16          // batches per WG (4 batch groups)
#define NJ 16          // hidden units per WG (64 j-tiles)
#define NR 64          // packed gate rows per WG (16 j x 4 gates, p = j*4+g)
#define KTOT 1280      // packed weight row: 256 (x) + 1024 (h)
#define HROWB 2048     // bytes per Hs row (128 units, bf16)
#define NFLAG 1024     // 4 groups x 64 gt x 4 waves
#define MAXTRY (1 << 20)

typedef __bf16 bf16x8 __attribute__((ext_vector_type(8)));
typedef float f32x4 __attribute__((ext_vector_type(4)));
typedef unsigned uint32x4 __attribute__((ext_vector_type(4)));
typedef unsigned uint32x2 __attribute__((ext_vector_type(2)));

__device__ inline uint32x4 ld16_sc1(const void* p) {
  uint32x4 r;
  asm volatile("global_load_dwordx4 %0, %1, off sc1" : "=&v"(r) : "v"(p));
  return r;
}

// ---------------- prep kernels ----------------

__global__ __launch_bounds__(256) void k_cast_inputs(const float* __restrict__ in,
                                                     __hip_bfloat16* __restrict__ outp) {
  int i = (blockIdx.x * 256 + threadIdx.x) * 4;
  float4 v = *reinterpret_cast<const float4*>(in + i);
  outp[i + 0] = __float2bfloat16(v.x);
  outp[i + 1] = __float2bfloat16(v.y);
  outp[i + 2] = __float2bfloat16(v.z);
  outp[i + 3] = __float2bfloat16(v.w);
}

// Packed row p = j*4 + gate (gate order i,f,g,o), cols [0:256)=Wx, [256:1280)=Wh
__global__ __launch_bounds__(256) void k_pack_w(
    const float* __restrict__ wxi, const float* __restrict__ whi,
    const float* __restrict__ wxf, const float* __restrict__ whf,
    const float* __restrict__ wxg, const float* __restrict__ whg,
    const float* __restrict__ wxo, const float* __restrict__ who,
    __hip_bfloat16* __restrict__ Wp) {
  int t = blockIdx.x * 256 + threadIdx.x;   // 0 .. 4096*320
  int p = t / 320;
  int k4 = (t - p * 320) * 4;
  int j = p >> 2, gate = p & 3;
  const float* wx = (gate == 0) ? wxi : (gate == 1) ? wxf : (gate == 2) ? wxg : wxo;
  const float* wh = (gate == 0) ? whi : (gate == 1) ? whf : (gate == 2) ? whg : who;
  float4 v;
  if (k4 < II) v = *reinterpret_cast<const float4*>(wx + (size_t)j * II + k4);
  else         v = *reinterpret_cast<const float4*>(wh + (size_t)j * HH + (k4 - II));
  __hip_bfloat16* o = Wp + (size_t)p * KTOT + k4;
  o[0] = __float2bfloat16(v.x);
  o[1] = __float2bfloat16(v.y);
  o[2] = __float2bfloat16(v.z);
  o[3] = __float2bfloat16(v.w);
}

__global__ __launch_bounds__(256) void k_pack_bias_h0(
    const float* __restrict__ bii, const float* __restrict__ bhi,
    const float* __restrict__ bif, const float* __restrict__ bhf,
    const float* __restrict__ bg,  const float* __restrict__ bhg,
    const float* __restrict__ bio, const float* __restrict__ bho,
    const float* __restrict__ h0, float* __restrict__ biasp,
    __hip_bfloat16* __restrict__ hb, unsigned* __restrict__ flags) {
  int i = blockIdx.x * 256 + threadIdx.x;   // 0..65535
  if (i < 4096) {
    int j = i >> 2, gate = i & 3;
    const float* bi = (gate == 0) ? bii : (gate == 1) ? bif : (gate == 2) ? bg : bio;
    const float* bh = (gate == 0) ? bhi : (gate == 1) ? bhf : (gate == 2) ? bhg : bho;
    biasp[i] = bi[j] + bh[j];
  }
  if (i < NFLAG) flags[i] = 0;
  hb[i] = __float2bfloat16(h0[i]);
}

// ---------------- persistent recurrent kernel ----------------
// R8 tiling/protocol (proven, 2181us). ONE delta: the wave's ENTIRE Wh slice
// (16 rows x 1280 k = 32 bf16x8 frags = 128 VGPRs) is parked in registers.
// Deletes 30 ds_read_b128/wave/step of loop-invariant Wl traffic (~half the
// CU's LDS-port time) and the whole Wl staging prologue. LDS shrinks to 38KB;
// we request 128KB dynamic LDS to keep the 1-WG/CU pinning (else dispatch
// could pack 4 WGs on 64 CUs and idle 192).

__global__ __launch_bounds__(256, 1) void k_lstm(
    const __hip_bfloat16* __restrict__ xb,
    const __hip_bfloat16* __restrict__ Wp,
    const float* __restrict__ biasp,
    const float* __restrict__ c0,
    __hip_bfloat16* __restrict__ hbuf,    // 2 x (B,H) bf16 ping-pong
    unsigned* __restrict__ flags,         // 4 groups x 64 gt x 4 waves
    float* __restrict__ out)
{
  extern __shared__ __align__(16) char smem[];
  char* Hs = smem;                        // 32768: staged h, 16 rows x 128 units bf16
  char* Zx = smem + 32768;                // 5120: per-wave z exchange
  char* Ho = smem + 37888;                // 512: per-wave h bounce (4 x 128B)

  const int tid = threadIdx.x;
  const int lane = tid & 63;
  const int wq = tid >> 6;
  const int bt = blockIdx.x >> 6;        // batch group 0..3
  const int gt = blockIdx.x & 63;        // j tile 0..63
  const int b0 = bt * MB;
  const int r0 = gt * NR;

  const int l15 = lane & 15;
  const int kqu = lane >> 4;             // 0..3 (16B unit within 32-k chunk)

  // ---- wave's weights in registers: Wx (8 frags) + FULL Wh (32 frags) ----
  const int brow = r0 + wq * 16 + l15;             // this lane's packed gate row
  bf16x8 wxr[8], whr[32];
  {
    const __hip_bfloat16* ws = Wp + (size_t)brow * KTOT + kqu * 8;
#pragma unroll
    for (int kk = 0; kk < 8; ++kk)
      wxr[kk] = *reinterpret_cast<const bf16x8*>(ws + kk * 32);
    const __hip_bfloat16* wh = ws + II;
#pragma unroll
    for (int kk = 0; kk < 32; ++kk)
      whr[kk] = *reinterpret_cast<const bf16x8*>(wh + kk * 32);
  }

  // ---- epilogue cell identity ----
  const int m_e = 4 * kqu + (lane & 3);            // batch 0..15
  const int tq = (lane >> 2) & 3;                  // j offset within wave
  const int j_g = gt * NJ + wq * 4 + tq;
  const int b_g = b0 + m_e;
  const float4 bias = *reinterpret_cast<const float4*>(biasp + j_g * 4);
  float c_reg = c0[(size_t)b_g * HH + j_g];

  // ---- fragment geometry ----
  const int hs_swz = l15 & 7;                      // A rows: batch = l15
  char* ZxW = Zx + wq * 1280;
  char* HoW = Ho + wq * 128;

  // ---- prologue: per-wave stage h(0) rows [wq*4,+4), coalesced sc1 ----
  {
    uint32x4 tmp[8];
#pragma unroll
    for (int q = 0; q < 8; ++q) {
      int idx = q * 64 + lane;                     // 0..511
      int rl = wq * 4 + (idx >> 7);
      int u = idx & 127;
      tmp[q] = ld16_sc1(hbuf + (size_t)(b0 + rl) * HH + u * 8);
    }
    asm volatile("s_waitcnt vmcnt(0)" ::: "memory");
    __builtin_amdgcn_sched_barrier(0);
#pragma unroll
    for (int q = 0; q < 8; ++q) {
      int idx = q * 64 + lane;
      int rl = wq * 4 + (idx >> 7);
      int u = idx & 127;
      *reinterpret_cast<uint32x4*>(Hs + rl * HROWB + ((u ^ (rl & 7)) << 4)) = tmp[q];
    }
  }

  // ---- prologue: x-part MFMA for t=0 ----
  const __hip_bfloat16* xrowA = xb + (size_t)(b0 + l15) * (TT * II) + kqu * 8;
  f32x4 accs[4];
#pragma unroll
  for (int q = 0; q < 4; ++q) accs[q] = (f32x4){0.f, 0.f, 0.f, 0.f};
#pragma unroll
  for (int kk = 0; kk < 8; ++kk) {
    bf16x8 xa = *reinterpret_cast<const bf16x8*>(xrowA + kk * 32);
    accs[kk & 3] = __builtin_amdgcn_mfma_f32_16x16x32_bf16(xa, wxr[kk], accs[kk & 3], 0, 0, 0);
  }

  __syncthreads();

  for (int t = 0; t < TT; ++t) {
    // ---- A: h-part MFMA (x-part already in accs); B entirely from regs ----
#pragma unroll
    for (int kk = 0; kk < 32; ++kk) {
      int u = kk * 4 + kqu;
      bf16x8 a = *reinterpret_cast<const bf16x8*>(Hs + l15 * HROWB + ((u ^ hs_swz) << 4));
      accs[kk & 3] = __builtin_amdgcn_mfma_f32_16x16x32_bf16(a, whr[kk], accs[kk & 3], 0, 0, 0);
    }
    f32x4 acc = (accs[0] + accs[1]) + (accs[2] + accs[3]);

    // ---- B: in-wave z exchange via LDS (drains this wave's Hs reads too) ----
    *reinterpret_cast<f32x4*>(ZxW + l15 * 80 + kqu * 16) = acc;
    asm volatile("s_waitcnt lgkmcnt(0)" ::: "memory");
    __builtin_amdgcn_sched_barrier(0);
    float zi = *reinterpret_cast<const float*>(ZxW + (4 * tq + 0) * 80 + m_e * 4) + bias.x;
    float zf = *reinterpret_cast<const float*>(ZxW + (4 * tq + 1) * 80 + m_e * 4) + bias.y;
    float zg = *reinterpret_cast<const float*>(ZxW + (4 * tq + 2) * 80 + m_e * 4) + bias.z;
    float zo = *reinterpret_cast<const float*>(ZxW + (4 * tq + 3) * 80 + m_e * 4) + bias.w;

    float ig = 1.f / (1.f + __expf(-zi));
    float fg = 1.f / (1.f + __expf(-zf));
    float gg = 2.f / (1.f + __expf(-2.f * zg)) - 1.f;
    float og = 1.f / (1.f + __expf(-zo));
    c_reg = fg * c_reg + ig * gg;
    float tc = 2.f / (1.f + __expf(-2.f * c_reg)) - 1.f;
    float h = og * tc;

    if (t == TT - 1) {
      out[(size_t)b_g * (TT * HH) + (size_t)t * HH + j_g] = h;
      out[(size_t)BB * TT * HH + (size_t)b_g * HH + j_g] = h;
      out[(size_t)BB * TT * HH + BB * HH + (size_t)b_g * HH + j_g] = c_reg;
      break;
    }

    // ---- C: h -> wave-local Ho bounce, publish 8B sc1, per-wave flag ----
    __hip_bfloat16 hb16 = __float2bfloat16(h);
    *reinterpret_cast<unsigned short*>(HoW + m_e * 8 + tq * 2) =
        *reinterpret_cast<unsigned short*>(&hb16);
    asm volatile("s_waitcnt lgkmcnt(0)" ::: "memory");
    __builtin_amdgcn_sched_barrier(0);

    const int nxt = (t + 1) & 1;
    const unsigned gen = (unsigned)(t + 1);
    if (lane < 16) {
      uint32x2 hv = *reinterpret_cast<const uint32x2*>(HoW + lane * 8);
      __hip_bfloat16* dst = hbuf + (size_t)nxt * (BB * HH)
                          + (size_t)(b0 + lane) * HH + gt * NJ + wq * 4;
      asm volatile("global_store_dwordx2 %0, %1, off sc1" :: "v"(dst), "v"(hv) : "memory");
    }
    asm volatile("s_waitcnt vmcnt(0)" ::: "memory");
    if (lane == 0) {
      asm volatile("global_store_dword %0, %1, off sc1"
                   :: "v"(flags + bt * 256 + gt * 4 + wq), "v"(gen) : "memory");
    }

    // ---- D: poll-window work: out store + x(t+1)-part MFMA ----
    out[(size_t)b_g * (TT * HH) + (size_t)t * HH + j_g] = h;
#pragma unroll
    for (int q = 0; q < 4; ++q) accs[q] = (f32x4){0.f, 0.f, 0.f, 0.f};
    {
      const __hip_bfloat16* xp = xrowA + (size_t)(t + 1) * II;
#pragma unroll
      for (int kk = 0; kk < 8; ++kk) {
        bf16x8 xa = *reinterpret_cast<const bf16x8*>(xp + kk * 32);
        accs[kk & 3] = __builtin_amdgcn_mfma_f32_16x16x32_bf16(xa, wxr[kk], accs[kk & 3], 0, 0, 0);
      }
    }

    // ---- E: every wave polls its group's 256 flags (4 per lane) ----
    {
      const unsigned* fp = flags + bt * 256 + lane * 4;
      int tries = 0;
      uint32x4 f;
      for (;;) {
        asm volatile("global_load_dwordx4 %0, %1, off sc1\n\ts_waitcnt vmcnt(0)"
                     : "=&v"(f) : "v"(fp) : "memory");
        int ok = (f.x >= gen) && (f.y >= gen) && (f.z >= gen) && (f.w >= gen);
        if (__all(ok) || ++tries > MAXTRY) break;
      }
    }

    // ---- F: per-wave stage h(t+1) rows [wq*4,+4), coalesced sc1 ----
    {
      uint32x4 tmp[8];
      const __hip_bfloat16* hsrc = hbuf + (size_t)nxt * (BB * HH);
#pragma unroll
      for (int q = 0; q < 8; ++q) {
        int idx = q * 64 + lane;
        int rl = wq * 4 + (idx >> 7);
        int u = idx & 127;
        tmp[q] = ld16_sc1(hsrc + (size_t)(b0 + rl) * HH + u * 8);
      }
      asm volatile("s_waitcnt vmcnt(0)" ::: "memory");
      __builtin_amdgcn_sched_barrier(0);
#pragma unroll
      for (int q = 0; q < 8; ++q) {
        int idx = q * 64 + lane;
        int rl = wq * 4 + (idx >> 7);
        int u = idx & 127;
        *reinterpret_cast<uint32x4*>(Hs + rl * HROWB + ((u ^ (rl & 7)) << 4)) = tmp[q];
      }
    }
    __syncthreads();                     // stage -> fragment-read handoff
  }
}

// ---------------- launcher ----------------

extern "C" void kernel_launch(void* const* d_in, const int* in_sizes, int n_in,
                              void* d_out, int out_size, void* d_ws, size_t ws_size,
                              hipStream_t stream) {
  (void)in_sizes; (void)n_in; (void)out_size; (void)ws_size;
  const float* inputs = (const float*)d_in[0];
  const float* h0 = (const float*)d_in[1];
  const float* c0 = (const float*)d_in[2];
  const float* w_ii = (const float*)d_in[3];
  const float* w_hi = (const float*)d_in[4];
  const float* b_ii = (const float*)d_in[5];
  const float* b_hi = (const float*)d_in[6];
  const float* w_if = (const float*)d_in[7];
  const float* w_hf = (const float*)d_in[8];
  const float* b_if = (const float*)d_in[9];
  const float* b_hf = (const float*)d_in[10];
  const float* w_io = (const float*)d_in[11];
  const float* w_ho = (const float*)d_in[12];
  const float* b_io = (const float*)d_in[13];
  const float* b_ho = (const float*)d_in[14];
  const float* w_ig = (const float*)d_in[15];
  const float* w_hg = (const float*)d_in[16];
  const float* b_ig = (const float*)d_in[17];
  const float* b_hg = (const float*)d_in[18];

  char* ws = (char*)d_ws;
  __hip_bfloat16* xb    = (__hip_bfloat16*)ws;                    // 16,777,216 B
  __hip_bfloat16* Wp    = (__hip_bfloat16*)(ws + 16777216);       // 10,485,760 B
  float*          biasp = (float*)(ws + 27262976);                // 16,384 B
  __hip_bfloat16* hbuf  = (__hip_bfloat16*)(ws + 27279360);       // 262,144 B
  unsigned*       flags = (unsigned*)(ws + 27541504);             // 4,096 B
  float* out = (float*)d_out;

  k_cast_inputs<<<8192, 256, 0, stream>>>(inputs, xb);
  k_pack_w<<<5120, 256, 0, stream>>>(w_ii, w_hi, w_if, w_hf, w_ig, w_hg, w_io, w_ho, Wp);
  k_pack_bias_h0<<<256, 256, 0, stream>>>(b_ii, b_hi, b_if, b_hf, b_ig, b_hg,
                                          b_io, b_ho, h0, biasp, hbuf, flags);

  // Request 128 KB dynamic LDS (actual use 38.4 KB) to pin 1 WG/CU:
  // otherwise the dispatcher could pack 4 WGs on 64 CUs and idle 192 CUs.
  const int lds_bytes = 131072;
  hipFuncSetAttribute((const void*)k_lstm,
                      hipFuncAttributeMaxDynamicSharedMemorySize, lds_bytes);
  void* args[] = {(void*)&xb, (void*)&Wp, (void*)&biasp, (void*)&c0,
                  (void*)&hbuf, (void*)&flags, (void*)&out};
  hipError_t e = hipLaunchCooperativeKernel((void*)k_lstm, dim3(NWG), dim3(256),
                                            args, lds_bytes, stream);
  if (e != hipSuccess) {
    // Fallback: plain launch. 256 WGs at 1 WG/CU (LDS-bound) on 256 CUs are
    // de-facto co-resident; the barrier protocol is flag-based only.
    k_lstm<<<dim3(NWG), dim3(256), lds_bytes, stream>>>(xb, Wp, biasp, c0, hbuf, flags, out);
  }
}